// Round 6
// baseline (274.821 us; speedup 1.0000x reference)
//
#include <hip/hip_runtime.h>
#include <hip/hip_fp16.h>
#include <stdint.h>

// ---------------------------------------------------------------------------
// ClusterPolicyNetwork: MHA (fp32) + pairwise task/node MLP (f16 MFMA)
// d_out (fp32): matching[1024*1024] | coord[32] | attn_w[1024*1024]
// Launches: proj_fused -> scores_kernel -> attn_mega -> score_kernel(+coord)
// ---------------------------------------------------------------------------

typedef __attribute__((ext_vector_type(4))) float floatx4;
typedef __attribute__((ext_vector_type(8))) _Float16 half8;

// workspace offsets (bytes)
#define OFF_QKV  0x000000u   // 1024*384*4
#define OFF_T1H  0x280000u   // 1024*256*2 (f16, includes +b1)
#define OFF_N1H  0x300000u   // 1024*256*2 (f16)
#define OFF_W2F  0x380000u   // 65536 (f16 MFMA frags)
#define OFF_GS   0x398000u   // 128*4
#define OFF_SC   0x400000u   // 4*1024*1024*4 raw scores

__device__ __forceinline__ unsigned pkadd(unsigned a, unsigned b) {
    unsigned r; asm("v_pk_add_f16 %0, %1, %2" : "=v"(r) : "v"(a), "v"(b)); return r;
}
__device__ __forceinline__ unsigned pkmax(unsigned a, unsigned b) {
    unsigned r; asm("v_pk_max_f16 %0, %1, %2" : "=v"(r) : "v"(a), "v"(b)); return r;
}
__device__ __forceinline__ unsigned pk2h(float a, float b) {
    return (unsigned)__half_as_ushort(__float2half(a)) |
           ((unsigned)__half_as_ushort(__float2half(b)) << 16);
}

// ---------------------------------------------------------------------------
// fp32 GEMM tile body: C = scale*(A @ B^T) [+ bias], 64x64 tile, 256 thr.
// ---------------------------------------------------------------------------
template<bool BIAS, bool F16OUT>
__device__ __forceinline__ void gemm_dev(
    const float* __restrict__ A, int lda,
    const float* __restrict__ B, int ldb,
    const float* __restrict__ bias,
    void* __restrict__ Cv, int ldc, int K, float scale,
    int m0, int n0, float (*As)[64], float (*Bs)[64])
{
    const int tid = threadIdx.x;
    const int tx = tid & 15, ty = tid >> 4;
    const int lr = tid >> 2;
    const int lk = (tid & 3) * 4;
    float c[4][4] = {};

    for (int k0 = 0; k0 < K; k0 += 16) {
        float4 a  = *(const float4*)&A[(long)(m0 + lr) * lda + k0 + lk];
        float4 bb = *(const float4*)&B[(long)(n0 + lr) * ldb + k0 + lk];
        __syncthreads();
        As[lk + 0][lr] = a.x;  As[lk + 1][lr] = a.y;  As[lk + 2][lr] = a.z;  As[lk + 3][lr] = a.w;
        Bs[lk + 0][lr] = bb.x; Bs[lk + 1][lr] = bb.y; Bs[lk + 2][lr] = bb.z; Bs[lk + 3][lr] = bb.w;
        __syncthreads();
#pragma unroll
        for (int k = 0; k < 16; k++) {
            float4 av = *(const float4*)&As[k][ty * 4];
            float4 bv = *(const float4*)&Bs[k][tx * 4];
            c[0][0] += av.x * bv.x; c[0][1] += av.x * bv.y; c[0][2] += av.x * bv.z; c[0][3] += av.x * bv.w;
            c[1][0] += av.y * bv.x; c[1][1] += av.y * bv.y; c[1][2] += av.y * bv.z; c[1][3] += av.y * bv.w;
            c[2][0] += av.z * bv.x; c[2][1] += av.z * bv.y; c[2][2] += av.z * bv.z; c[2][3] += av.z * bv.w;
            c[3][0] += av.w * bv.x; c[3][1] += av.w * bv.y; c[3][2] += av.w * bv.z; c[3][3] += av.w * bv.w;
        }
    }

    float bsv[4] = {0.f, 0.f, 0.f, 0.f};
    if (BIAS) {
        float4 t = *(const float4*)&bias[n0 + tx * 4];
        bsv[0] = t.x; bsv[1] = t.y; bsv[2] = t.z; bsv[3] = t.w;
    }
#pragma unroll
    for (int i = 0; i < 4; i++) {
        float v0 = c[i][0] * scale + bsv[0];
        float v1 = c[i][1] * scale + bsv[1];
        float v2 = c[i][2] * scale + bsv[2];
        float v3 = c[i][3] * scale + bsv[3];
        long m = m0 + ty * 4 + i;
        if (F16OUT) {
            unsigned short* Cp = (unsigned short*)Cv;
            ushort4 o;
            o.x = __half_as_ushort(__float2half(v0));
            o.y = __half_as_ushort(__float2half(v1));
            o.z = __half_as_ushort(__float2half(v2));
            o.w = __half_as_ushort(__float2half(v3));
            *(ushort4*)&Cp[m * ldc + n0 + tx * 4] = o;
        } else {
            float* Cp = (float*)Cv;
            *(float4*)&Cp[m * ldc + n0 + tx * 4] = make_float4(v0, v1, v2, v3);
        }
    }
}

// ---------------------------------------------------------------------------
// Launch 1: qkv gemm (96) + t1h gemm (64) + w2prep (16) + gs zero (1)
// ---------------------------------------------------------------------------
__launch_bounds__(256)
__global__ void proj_fused(const float* __restrict__ node, const float* __restrict__ ipw,
                           const float* __restrict__ ipb,
                           const float* __restrict__ task, const float* __restrict__ W1,
                           const float* __restrict__ b1, const float* __restrict__ W2,
                           float* __restrict__ qkv, unsigned short* __restrict__ t1h,
                           unsigned short* __restrict__ w2f, float* __restrict__ gs)
{
    __shared__ float As[16][64], Bs[16][64];
    const int bid = blockIdx.x;
    if (bid < 96) {
        gemm_dev<true, false>(node, 128, ipw, 128, ipb, qkv, 384, 128, 1.0f,
                              (bid & 15) * 64, (bid >> 4) * 64, As, Bs);
    } else if (bid < 160) {
        const int b = bid - 96;
        gemm_dev<true, true>(task, 128, W1, 256, b1, t1h, 256, 128, 1.0f,
                             (b & 15) * 64, (b >> 4) * 64, As, Bs);
    } else if (bid < 176) {
        // W2 -> f16 MFMA fragment layout:
        // frag[((cc*8+ot)*64+lane)*8+j] = f16(W2[ot*16+(lane&15)][cc*32+(lane>>4)*8+j])
        const int gtid = (bid - 160) * 256 + threadIdx.x;  // 0..4095
        const int lane = gtid & 63, frag = gtid >> 6;
        const int cc = frag >> 3, ot = frag & 7;
        const float* src = &W2[(ot * 16 + (lane & 15)) * 256 + cc * 32 + (lane >> 4) * 8];
        uint4 o;
        o.x = pk2h(src[0], src[1]);
        o.y = pk2h(src[2], src[3]);
        o.z = pk2h(src[4], src[5]);
        o.w = pk2h(src[6], src[7]);
        ((uint4*)w2f)[gtid] = o;
    } else {
        if (threadIdx.x < 128) gs[threadIdx.x] = 0.f;
    }
}

// ---------------------------------------------------------------------------
// Launch 2: scores[h] = Qh @ Kh^T / sqrt(32), grid (16,16,4)
// ---------------------------------------------------------------------------
__launch_bounds__(256)
__global__ void scores_kernel(const float* __restrict__ qkv, float* __restrict__ sc)
{
    __shared__ float As[16][64], Bs[16][64];
    const int h = blockIdx.z;
    gemm_dev<false, false>(qkv + h * 32, 384, qkv + 128 + h * 32, 384, nullptr,
                           sc + (long)h * 1048576, 1024, 32, 0.17677669529663687f,
                           blockIdx.x * 64, blockIdx.y * 64, As, Bs);
}

// ---------------------------------------------------------------------------
// Launch 3: attn_mega — per block 4 q-rows, 256 blocks (1/CU).
// stats + attn_w + ctx + out-proj + gs col-sums + n1h, all row-local.
// ---------------------------------------------------------------------------
__launch_bounds__(256)
__global__ void attn_mega(const float* __restrict__ sc, const float* __restrict__ qkv,
                          const float* __restrict__ outw, const float* __restrict__ outb,
                          const float* __restrict__ W1,
                          float* __restrict__ attn_out, unsigned short* __restrict__ n1h,
                          float* __restrict__ gs)
{
    __shared__ unsigned short Ps[16 * 1024];   // [h*4+q][k] f16 scores -> probs (32 KB)
    __shared__ float ctp[2][4][128];           // ctx ksplit partials
    __shared__ float attr[4][128];             // attended rows
    __shared__ float stm[16], stl[16];
    const int t = threadIdx.x;
    const int q0 = blockIdx.x * 4;

    // phase 1: stage raw scores as f16
#pragma unroll
    for (int r = 0; r < 16; r++) {
        const int h = r >> 2, q = r & 3;
        float4 v = *(const float4*)&sc[(long)h * 1048576 + (long)(q0 + q) * 1024 + t * 4];
        ushort4 o;
        o.x = __half_as_ushort(__float2half(v.x));
        o.y = __half_as_ushort(__float2half(v.y));
        o.z = __half_as_ushort(__float2half(v.z));
        o.w = __half_as_ushort(__float2half(v.w));
        *(ushort4*)&Ps[r * 1024 + t * 4] = o;
    }
    __syncthreads();

    // phase 2: row stats (wave = head h; full-wave reduction per q)
    {
        const int h = t >> 6, ln = t & 63;
#pragma unroll
        for (int q = 0; q < 4; q++) {
            const int base = (h * 4 + q) * 1024 + ln * 16;
            float v[16];
            float mx = -1e30f;
#pragma unroll
            for (int i = 0; i < 8; i++) {
                float2 f = __half22float2(*(const __half2*)&Ps[base + i * 2]);
                v[2 * i] = f.x; v[2 * i + 1] = f.y;
                mx = fmaxf(mx, fmaxf(f.x, f.y));
            }
#pragma unroll
            for (int m = 1; m < 64; m <<= 1) mx = fmaxf(mx, __shfl_xor(mx, m));
            float s = 0.f;
#pragma unroll
            for (int i = 0; i < 16; i++) s += __expf(v[i] - mx);
#pragma unroll
            for (int m = 1; m < 64; m <<= 1) s += __shfl_xor(s, m);
            if (ln == 0) { stm[h * 4 + q] = mx; stl[h * 4 + q] = s; }
        }
    }
    __syncthreads();

    // phase 3: normalize in place (f16) + head-averaged attn output
    {
        float acc[4][4] = {};
#pragma unroll
        for (int r = 0; r < 16; r++) {
            const int q = r & 3;
            const float m = stm[r], il = 1.0f / stl[r];
            ushort4 u = *(const ushort4*)&Ps[r * 1024 + t * 4];
            float p0 = __expf(__half2float(__ushort_as_half(u.x)) - m) * il;
            float p1 = __expf(__half2float(__ushort_as_half(u.y)) - m) * il;
            float p2 = __expf(__half2float(__ushort_as_half(u.z)) - m) * il;
            float p3 = __expf(__half2float(__ushort_as_half(u.w)) - m) * il;
            ushort4 o;
            o.x = __half_as_ushort(__float2half(p0));
            o.y = __half_as_ushort(__float2half(p1));
            o.z = __half_as_ushort(__float2half(p2));
            o.w = __half_as_ushort(__float2half(p3));
            *(ushort4*)&Ps[r * 1024 + t * 4] = o;
            acc[q][0] += 0.25f * p0; acc[q][1] += 0.25f * p1;
            acc[q][2] += 0.25f * p2; acc[q][3] += 0.25f * p3;
        }
#pragma unroll
        for (int q = 0; q < 4; q++)
            *(float4*)&attn_out[(long)(q0 + q) * 1024 + t * 4] =
                make_float4(acc[q][0], acc[q][1], acc[q][2], acc[q][3]);
    }
    __syncthreads();

    // phase 4: ctx = P @ V. thread = (hd = h*32+d, ks); V reads lane-coalesced.
    {
        const int hd = t & 127, ks = t >> 7;
        const int h = hd >> 5;
        float ca[4] = {};
        const float* vp = qkv + 256 + hd;
        for (int k0 = ks * 512; k0 < ks * 512 + 512; k0 += 4) {
            float v0 = vp[(long)(k0 + 0) * 384];
            float v1 = vp[(long)(k0 + 1) * 384];
            float v2 = vp[(long)(k0 + 2) * 384];
            float v3 = vp[(long)(k0 + 3) * 384];
#pragma unroll
            for (int q = 0; q < 4; q++) {
                float2 fa = __half22float2(*(const __half2*)&Ps[(h * 4 + q) * 1024 + k0]);
                float2 fb = __half22float2(*(const __half2*)&Ps[(h * 4 + q) * 1024 + k0 + 2]);
                ca[q] += fa.x * v0 + fa.y * v1 + fb.x * v2 + fb.y * v3;
            }
        }
#pragma unroll
        for (int q = 0; q < 4; q++) ctp[ks][q][hd] = ca[q];
    }
    __syncthreads();
    {
        float* cf = &ctp[0][0][0];
        cf[t] += cf[t + 512];
        cf[t + 256] += cf[t + 768];
    }
    __syncthreads();

    // phase 5: attended rows = ctx @ outw^T + outb (row-local)
    {
        const int j = t & 127, qp = t >> 7;
        float a0 = outb[j], a1 = a0;
        const float* wr = &outw[j * 128];
        for (int d = 0; d < 128; d += 4) {
            float4 w  = *(const float4*)&wr[d];
            float4 c0 = *(const float4*)&ctp[0][qp * 2 + 0][d];
            float4 c1 = *(const float4*)&ctp[0][qp * 2 + 1][d];
            a0 += w.x * c0.x + w.y * c0.y + w.z * c0.z + w.w * c0.w;
            a1 += w.x * c1.x + w.y * c1.y + w.z * c1.z + w.w * c1.w;
        }
        attr[qp * 2 + 0][j] = a0;
        attr[qp * 2 + 1][j] = a1;
    }
    __syncthreads();
    if (t < 128) atomicAdd(&gs[t], attr[0][t] + attr[1][t] + attr[2][t] + attr[3][t]);

    // phase 6: n1h rows = attended @ W1[:,128:]^T (f16 out, no bias)
    {
        const int c = t;
        const float* wr = &W1[c * 256 + 128];
        float n[4] = {};
        for (int d = 0; d < 128; d += 4) {
            float4 w = *(const float4*)&wr[d];
#pragma unroll
            for (int q = 0; q < 4; q++) {
                float4 a = *(const float4*)&attr[q][d];
                n[q] += w.x * a.x + w.y * a.y + w.z * a.z + w.w * a.w;
            }
        }
#pragma unroll
        for (int q = 0; q < 4; q++)
            n1h[(long)(q0 + q) * 256 + c] = __half_as_ushort(__float2half(n[q]));
    }
}

// ---------------------------------------------------------------------------
// Launch 4: matching scores (grid 16x33; y==32 hosts coord head).
// Swapped-operand MFMA (kout on quad/reg axis). t1-tile staged in LDS (16 KB)
// to keep the per-cc h1-build chain on short LDS latency; W2 frags hybrid:
// cc 0..4 from LDS (40 KB), cc 5..7 from global (L2-resident 24 KB).
// Zero acc init; b2 applied in epilogue from LDS table.
// ---------------------------------------------------------------------------
__launch_bounds__(256, 2)
__global__ void score_kernel(const unsigned short* __restrict__ t1h,
                             const unsigned short* __restrict__ n1h,
                             const unsigned short* __restrict__ w2f,
                             const float* __restrict__ b2, const float* __restrict__ W3,
                             const float* __restrict__ b3, float* __restrict__ out,
                             const float* __restrict__ gs,
                             const float* __restrict__ Wc1, const float* __restrict__ bc1,
                             const float* __restrict__ Wc2, const float* __restrict__ bc2,
                             float* __restrict__ outc)
{
    __shared__ unsigned short w2s[20480];   // 40 KB: cc 0..4 fragments
    __shared__ unsigned short t1s[8192];    // 16 KB: 32 t-rows x 256 k
    __shared__ float b2s[128], w3s[128];
    const int tid = threadIdx.x;

    if (blockIdx.y == 32) {
        // coordination head (reuses t1s as scratch)
        if (blockIdx.x != 0) return;
        float* g  = (float*)t1s;
        float* hh = g + 128;
        if (tid < 128) g[tid] = gs[tid] * (1.0f / 1024.0f);
        __syncthreads();
        {
            float a = bc1[tid];
            const float* wr = &Wc1[tid * 128];
            for (int d = 0; d < 128; d += 4) {
                float4 w = *(const float4*)&wr[d];
                a += w.x * g[d] + w.y * g[d + 1] + w.z * g[d + 2] + w.w * g[d + 3];
            }
            hh[tid] = fmaxf(a, 0.f);
        }
        __syncthreads();
        if (tid < 32) {
            float a = bc2[tid];
            const float* wr = &Wc2[tid * 256];
            for (int c = 0; c < 256; c += 4) {
                float4 w = *(const float4*)&wr[c];
                a += w.x * hh[c] + w.y * hh[c + 1] + w.z * hh[c + 2] + w.w * hh[c + 3];
            }
            outc[tid] = a;
        }
        return;
    }

    const int lane = tid & 63;
    const int wv = tid >> 6;
    const int col = lane & 15;
    const int quad = lane >> 4;
    const int nb = blockIdx.x * 64 + wv * 16;
    const int tb = blockIdx.y * 32;

    // stage: W2 cc 0..4 (2560 uint4) + t1 tile (2048 uint4) + tables
    {
        const uint4* src = (const uint4*)w2f;
        uint4* dst = (uint4*)w2s;
#pragma unroll
        for (int i = 0; i < 10; i++) dst[tid + i * 256] = src[tid + i * 256];
        uint4* t1dst = (uint4*)t1s;
#pragma unroll
        for (int i = 0; i < 8; i++) {
            const int j = tid + i * 256;
            t1dst[j] = *(const uint4*)(t1h + (long)(tb + (j >> 5)) * 256 + (j & 31) * 8);
        }
        if (tid < 128) { b2s[tid] = b2[tid]; w3s[tid] = W3[tid]; }
    }

    // n1 slice for this lane (16 n-rows per wave), all K=256: 32 VGPRs
    const int myn = nb + col;
    uint4 n1p[8];
#pragma unroll
    for (int cc = 0; cc < 8; cc++)
        n1p[cc] = *(const uint4*)(n1h + (long)myn * 256 + cc * 32 + quad * 8);

    const float b3s = b3[0];
    __syncthreads();

    for (int tg = 0; tg < 8; tg++) {
        floatx4 acc[4][8] = {};   // zero init: no load dependency at tg start

#pragma unroll
        for (int cc = 0; cc < 8; cc++) {
            // t-frags from LDS (broadcast: 4 distinct addresses per wave)
            uint4 tp[4];
#pragma unroll
            for (int tt = 0; tt < 4; tt++)
                tp[tt] = *(const uint4*)&t1s[(tg * 4 + tt) * 256 + cc * 32 + quad * 8];

            const unsigned* npu = (const unsigned*)&n1p[cc];
            union { unsigned u[4]; half8 h; } af[4];
#pragma unroll
            for (int tt = 0; tt < 4; tt++) {
                const unsigned* tpu = (const unsigned*)&tp[tt];
#pragma unroll
                for (int p = 0; p < 4; p++)
                    af[tt].u[p] = pkmax(pkadd(tpu[p], npu[p]), 0u);
            }
#pragma unroll
            for (int ot = 0; ot < 8; ot++) {
                union { uint4 u; half8 h; } bf;
                if (cc < 5)
                    bf.u = *(const uint4*)&w2s[((cc * 8 + ot) * 64 + lane) * 8];
                else
                    bf.u = *(const uint4*)(w2f + ((size_t)((cc * 8 + ot) * 64 + lane)) * 8);
#pragma unroll
                for (int tt = 0; tt < 4; tt++)   // A = W2-frag, B = h1-frag
                    acc[tt][ot] = __builtin_amdgcn_mfma_f32_16x16x32_f16(bf.h, af[tt].h, acc[tt][ot], 0, 0, 0);
            }
        }

        // epilogue: b2 + relu + W3 (LDS broadcast), in-lane reduce + 2 shuffles
        float part[4] = {0.f, 0.f, 0.f, 0.f};
#pragma unroll
        for (int ot = 0; ot < 8; ot++) {
            float4 bq = *(const float4*)&b2s[ot * 16 + quad * 4];
            float4 wq = *(const float4*)&w3s[ot * 16 + quad * 4];
#pragma unroll
            for (int tt = 0; tt < 4; tt++) {
                floatx4 a = acc[tt][ot];
                part[tt] += fmaxf(a[0] + bq.x, 0.f) * wq.x + fmaxf(a[1] + bq.y, 0.f) * wq.y
                          + fmaxf(a[2] + bq.z, 0.f) * wq.z + fmaxf(a[3] + bq.w, 0.f) * wq.w;
            }
        }
        float outv = 0.f;
#pragma unroll
        for (int tt = 0; tt < 4; tt++) {
            float p = part[tt];
            p += __shfl_xor(p, 16);
            p += __shfl_xor(p, 32);
            if (quad == tt) outv = p;   // quad q keeps t = tg*4 + q
        }
        out[(long)(tb + tg * 4 + quad) * 1024 + nb + col] =
            1.0f / (1.0f + __expf(-(outv + b3s)));
    }
}

// ---------------------------------------------------------------------------
extern "C" void kernel_launch(void* const* d_in, const int* in_sizes, int n_in,
                              void* d_out, int out_size, void* d_ws, size_t ws_size,
                              hipStream_t stream)
{
    const float* node = (const float*)d_in[0];
    const float* task = (const float*)d_in[1];
    const float* ipw  = (const float*)d_in[2];
    const float* ipb  = (const float*)d_in[3];
    const float* outw = (const float*)d_in[4];
    const float* outb = (const float*)d_in[5];
    const float* W1   = (const float*)d_in[6];
    const float* b1   = (const float*)d_in[7];
    const float* W2   = (const float*)d_in[8];
    const float* b2   = (const float*)d_in[9];
    const float* W3   = (const float*)d_in[10];
    const float* b3   = (const float*)d_in[11];
    const float* Wc1  = (const float*)d_in[12];
    const float* bc1  = (const float*)d_in[13];
    const float* Wc2  = (const float*)d_in[14];
    const float* bc2  = (const float*)d_in[15];

    char* ws = (char*)d_ws;
    float* qkv = (float*)(ws + OFF_QKV);
    float* sc  = (float*)(ws + OFF_SC);
    unsigned short* t1h = (unsigned short*)(ws + OFF_T1H);
    unsigned short* n1h = (unsigned short*)(ws + OFF_N1H);
    unsigned short* w2f = (unsigned short*)(ws + OFF_W2F);
    float* gs = (float*)(ws + OFF_GS);

    float* out_match = (float*)d_out;
    float* out_coord = out_match + 1048576;
    float* out_attn  = out_coord + 32;

    // 1. qkv + t1h + w2prep + gs zero
    proj_fused<<<dim3(177, 1, 1), 256, 0, stream>>>(
        node, ipw, ipb, task, W1, b1, W2, qkv, t1h, w2f, gs);
    // 2. raw scores
    scores_kernel<<<dim3(16, 16, 4), 256, 0, stream>>>(qkv, sc);
    // 3. stats + attn_w + ctx + out-proj + gs + n1h
    attn_mega<<<dim3(256, 1, 1), 256, 0, stream>>>(
        sc, qkv, outw, outb, W1, out_attn, n1h, gs);
    // 4. matching scores + coord head
    score_kernel<<<dim3(16, 33, 1), 256, 0, stream>>>(
        t1h, n1h, w2f, b2, W3, b3, out_match,
        gs, Wc1, bc1, Wc2, bc2, out_coord);
}

// Round 7
// 212.647 us; speedup vs baseline: 1.2924x; 1.2924x over previous
//
#include <hip/hip_runtime.h>
#include <hip/hip_fp16.h>
#include <stdint.h>

// ---------------------------------------------------------------------------
// ClusterPolicyNetwork: MHA (f16 score matrix, fp32 softmax/ctx) + pairwise
// MLP (f16 MFMA). d_out (fp32): matching[1M] | coord[32] | attn_w[1M]
// Launches: memset(ctx) -> proj_fused -> scores(f16) -> attn_pre -> ctx_kernel
//           -> attn_post -> score_kernel(+coord)
// ---------------------------------------------------------------------------

typedef __attribute__((ext_vector_type(4))) float floatx4;
typedef __attribute__((ext_vector_type(8))) _Float16 half8;

// workspace offsets (bytes)
#define OFF_QKV  0x000000u    // 1024*384*4 = 1.5 MB
#define OFF_CTX  0x180000u    // 1024*128*4 = 512 KB
#define OFF_T1H  0x280000u    // 1024*256*2 (f16, includes +b1)
#define OFF_N1H  0x300000u    // 1024*256*2 (f16)
#define OFF_W2F  0x380000u    // 65536 (f16 MFMA frags)
#define OFF_GS   0x398000u    // 128*4
#define OFF_SC   0x400000u    // 4*1024*1024*2 = 8 MB f16 raw scores
#define OFF_PG   0xC00000u    // 4*1024*1024*2 = 8 MB f16 probs

__device__ __forceinline__ unsigned pkadd(unsigned a, unsigned b) {
    unsigned r; asm("v_pk_add_f16 %0, %1, %2" : "=v"(r) : "v"(a), "v"(b)); return r;
}
__device__ __forceinline__ unsigned pkmax(unsigned a, unsigned b) {
    unsigned r; asm("v_pk_max_f16 %0, %1, %2" : "=v"(r) : "v"(a), "v"(b)); return r;
}
__device__ __forceinline__ unsigned pk2h(float a, float b) {
    return (unsigned)__half_as_ushort(__float2half(a)) |
           ((unsigned)__half_as_ushort(__float2half(b)) << 16);
}
__device__ __forceinline__ float h2f(unsigned short u) {
    return __half2float(__ushort_as_half(u));
}

// ---------------------------------------------------------------------------
// fp32 GEMM tile body: C = scale*(A @ B^T) [+ bias], 64x64 tile, 256 thr.
// ---------------------------------------------------------------------------
template<bool BIAS, bool F16OUT>
__device__ __forceinline__ void gemm_dev(
    const float* __restrict__ A, int lda,
    const float* __restrict__ B, int ldb,
    const float* __restrict__ bias,
    void* __restrict__ Cv, int ldc, int K, float scale,
    int m0, int n0, float (*As)[64], float (*Bs)[64])
{
    const int tid = threadIdx.x;
    const int tx = tid & 15, ty = tid >> 4;
    const int lr = tid >> 2;
    const int lk = (tid & 3) * 4;
    float c[4][4] = {};

    for (int k0 = 0; k0 < K; k0 += 16) {
        float4 a  = *(const float4*)&A[(long)(m0 + lr) * lda + k0 + lk];
        float4 bb = *(const float4*)&B[(long)(n0 + lr) * ldb + k0 + lk];
        __syncthreads();
        As[lk + 0][lr] = a.x;  As[lk + 1][lr] = a.y;  As[lk + 2][lr] = a.z;  As[lk + 3][lr] = a.w;
        Bs[lk + 0][lr] = bb.x; Bs[lk + 1][lr] = bb.y; Bs[lk + 2][lr] = bb.z; Bs[lk + 3][lr] = bb.w;
        __syncthreads();
#pragma unroll
        for (int k = 0; k < 16; k++) {
            float4 av = *(const float4*)&As[k][ty * 4];
            float4 bv = *(const float4*)&Bs[k][tx * 4];
            c[0][0] += av.x * bv.x; c[0][1] += av.x * bv.y; c[0][2] += av.x * bv.z; c[0][3] += av.x * bv.w;
            c[1][0] += av.y * bv.x; c[1][1] += av.y * bv.y; c[1][2] += av.y * bv.z; c[1][3] += av.y * bv.w;
            c[2][0] += av.z * bv.x; c[2][1] += av.z * bv.y; c[2][2] += av.z * bv.z; c[2][3] += av.z * bv.w;
            c[3][0] += av.w * bv.x; c[3][1] += av.w * bv.y; c[3][2] += av.w * bv.z; c[3][3] += av.w * bv.w;
        }
    }

    float bsv[4] = {0.f, 0.f, 0.f, 0.f};
    if (BIAS) {
        float4 t = *(const float4*)&bias[n0 + tx * 4];
        bsv[0] = t.x; bsv[1] = t.y; bsv[2] = t.z; bsv[3] = t.w;
    }
#pragma unroll
    for (int i = 0; i < 4; i++) {
        float v0 = c[i][0] * scale + bsv[0];
        float v1 = c[i][1] * scale + bsv[1];
        float v2 = c[i][2] * scale + bsv[2];
        float v3 = c[i][3] * scale + bsv[3];
        long m = m0 + ty * 4 + i;
        if (F16OUT) {
            unsigned short* Cp = (unsigned short*)Cv;
            ushort4 o;
            o.x = __half_as_ushort(__float2half(v0));
            o.y = __half_as_ushort(__float2half(v1));
            o.z = __half_as_ushort(__float2half(v2));
            o.w = __half_as_ushort(__float2half(v3));
            *(ushort4*)&Cp[m * ldc + n0 + tx * 4] = o;
        } else {
            float* Cp = (float*)Cv;
            *(float4*)&Cp[m * ldc + n0 + tx * 4] = make_float4(v0, v1, v2, v3);
        }
    }
}

// ---------------------------------------------------------------------------
// Launch 1: qkv gemm (96) + t1h gemm (64) + w2prep (16) + gs zero (1)
// ---------------------------------------------------------------------------
__launch_bounds__(256)
__global__ void proj_fused(const float* __restrict__ node, const float* __restrict__ ipw,
                           const float* __restrict__ ipb,
                           const float* __restrict__ task, const float* __restrict__ W1,
                           const float* __restrict__ b1, const float* __restrict__ W2,
                           float* __restrict__ qkv, unsigned short* __restrict__ t1h,
                           unsigned short* __restrict__ w2f, float* __restrict__ gs)
{
    __shared__ float As[16][64], Bs[16][64];
    const int bid = blockIdx.x;
    if (bid < 96) {
        gemm_dev<true, false>(node, 128, ipw, 128, ipb, qkv, 384, 128, 1.0f,
                              (bid & 15) * 64, (bid >> 4) * 64, As, Bs);
    } else if (bid < 160) {
        const int b = bid - 96;
        gemm_dev<true, true>(task, 128, W1, 256, b1, t1h, 256, 128, 1.0f,
                             (b & 15) * 64, (b >> 4) * 64, As, Bs);
    } else if (bid < 176) {
        // W2 -> f16 MFMA fragment layout:
        // frag[((cc*8+ot)*64+lane)*8+j] = f16(W2[ot*16+(lane&15)][cc*32+(lane>>4)*8+j])
        const int gtid = (bid - 160) * 256 + threadIdx.x;  // 0..4095
        const int lane = gtid & 63, frag = gtid >> 6;
        const int cc = frag >> 3, ot = frag & 7;
        const float* src = &W2[(ot * 16 + (lane & 15)) * 256 + cc * 32 + (lane >> 4) * 8];
        uint4 o;
        o.x = pk2h(src[0], src[1]);
        o.y = pk2h(src[2], src[3]);
        o.z = pk2h(src[4], src[5]);
        o.w = pk2h(src[6], src[7]);
        ((uint4*)w2f)[gtid] = o;
    } else {
        if (threadIdx.x < 128) gs[threadIdx.x] = 0.f;
    }
}

// ---------------------------------------------------------------------------
// Launch 2: scores[h] = Qh @ Kh^T / sqrt(32) -> f16, grid (16,16,4)
// ---------------------------------------------------------------------------
__launch_bounds__(256)
__global__ void scores_kernel(const float* __restrict__ qkv, unsigned short* __restrict__ sc16)
{
    __shared__ float As[16][64], Bs[16][64];
    const int h = blockIdx.z;
    gemm_dev<false, true>(qkv + h * 32, 384, qkv + 128 + h * 32, 384, nullptr,
                          sc16 + ((size_t)h << 20), 1024, 32, 0.17677669529663687f,
                          blockIdx.x * 64, blockIdx.y * 64, As, Bs);
}

// ---------------------------------------------------------------------------
// Launch 3: attn_pre — 1024 blocks, one q-row each: softmax stats over f16
// scores, write f16 probs Pg + fp32 attn_w (head-averaged).
// ---------------------------------------------------------------------------
__launch_bounds__(256)
__global__ void attn_pre(const unsigned short* __restrict__ sc16,
                         unsigned short* __restrict__ Pg, float* __restrict__ attn_out)
{
    __shared__ float Ps[4][1024];   // 16 KB
    __shared__ float stm[4], stl[4];
    const int t = threadIdx.x;
    const int q = blockIdx.x;

    // stage + dequant (coalesced 8B/lane)
#pragma unroll
    for (int h = 0; h < 4; h++) {
        ushort4 u = *(const ushort4*)&sc16[((size_t)h << 20) + (size_t)q * 1024 + t * 4];
        float4 f = make_float4(h2f(u.x), h2f(u.y), h2f(u.z), h2f(u.w));
        *(float4*)&Ps[h][t * 4] = f;
    }
    __syncthreads();

    // wave wv handles row h = wv: strided float4 reads, conflict-free
    {
        const int h = t >> 6, ln = t & 63;
        float4 v[4];
        float mx = -1e30f;
#pragma unroll
        for (int i = 0; i < 4; i++) {
            v[i] = *(const float4*)&Ps[h][ln * 4 + i * 256];
            mx = fmaxf(mx, fmaxf(fmaxf(v[i].x, v[i].y), fmaxf(v[i].z, v[i].w)));
        }
#pragma unroll
        for (int m = 1; m < 64; m <<= 1) mx = fmaxf(mx, __shfl_xor(mx, m));
        float s = 0.f;
#pragma unroll
        for (int i = 0; i < 4; i++)
            s += __expf(v[i].x - mx) + __expf(v[i].y - mx) +
                 __expf(v[i].z - mx) + __expf(v[i].w - mx);
#pragma unroll
        for (int m = 1; m < 64; m <<= 1) s += __shfl_xor(s, m);
        if (ln == 0) { stm[h] = mx; stl[h] = s; }
    }
    __syncthreads();

    float a0 = 0.f, a1 = 0.f, a2 = 0.f, a3 = 0.f;
#pragma unroll
    for (int h = 0; h < 4; h++) {
        const float m = stm[h], il = 1.0f / stl[h];
        float4 f = *(const float4*)&Ps[h][t * 4];
        float p0 = __expf(f.x - m) * il, p1 = __expf(f.y - m) * il;
        float p2 = __expf(f.z - m) * il, p3 = __expf(f.w - m) * il;
        ushort4 o;
        o.x = __half_as_ushort(__float2half(p0));
        o.y = __half_as_ushort(__float2half(p1));
        o.z = __half_as_ushort(__float2half(p2));
        o.w = __half_as_ushort(__float2half(p3));
        *(ushort4*)&Pg[((size_t)h << 20) + (size_t)q * 1024 + t * 4] = o;
        a0 += p0; a1 += p1; a2 += p2; a3 += p3;
    }
    *(float4*)&attn_out[(size_t)q * 1024 + t * 4] =
        make_float4(0.25f * a0, 0.25f * a1, 0.25f * a2, 0.25f * a3);
}

// ---------------------------------------------------------------------------
// Launch 4: ctx = P @ V (f16 probs), split-k over 8 chunks, fp32 atomicAdd.
// grid (16 qtiles, 8 ksplit, 4 heads) — r2-proven structure.
// ---------------------------------------------------------------------------
__launch_bounds__(256)
__global__ void ctx_kernel(const unsigned short* __restrict__ Pg,
                           const float* __restrict__ qkv, float* __restrict__ ctx)
{
    const int h = blockIdx.z;
    const int q0 = blockIdx.x * 64;
    const int kbase = blockIdx.y * 128;
    __shared__ float As[32][64];
    __shared__ float Vs[32][32];
    const int tid = threadIdx.x;
    const int tx = tid & 15, ty = tid >> 4;
    const int sq = tid >> 3;
    const int sk4 = (tid & 7) * 4;
    float acc[4][2] = {};

    for (int k0 = kbase; k0 < kbase + 128; k0 += 32) {
        __syncthreads();
#pragma unroll
        for (int half = 0; half < 2; half++) {
            int q = sq + half * 32;
            ushort4 u = *(const ushort4*)&Pg[((size_t)h << 20) + (size_t)(q0 + q) * 1024 + k0 + sk4];
            As[sk4 + 0][q] = h2f(u.x);
            As[sk4 + 1][q] = h2f(u.y);
            As[sk4 + 2][q] = h2f(u.z);
            As[sk4 + 3][q] = h2f(u.w);
        }
        *(float4*)&Vs[sq][sk4] = *(const float4*)&qkv[(long)(k0 + sq) * 384 + 256 + h * 32 + sk4];
        __syncthreads();
#pragma unroll
        for (int k = 0; k < 32; k++) {
            float4 a = *(const float4*)&As[k][tx * 4];
            float b0 = Vs[k][ty * 2], b1 = Vs[k][ty * 2 + 1];
            acc[0][0] += a.x * b0; acc[0][1] += a.x * b1;
            acc[1][0] += a.y * b0; acc[1][1] += a.y * b1;
            acc[2][0] += a.z * b0; acc[2][1] += a.z * b1;
            acc[3][0] += a.w * b0; acc[3][1] += a.w * b1;
        }
    }
#pragma unroll
    for (int i = 0; i < 4; i++) {
        atomicAdd(&ctx[(long)(q0 + tx * 4 + i) * 128 + h * 32 + ty * 2 + 0], acc[i][0]);
        atomicAdd(&ctx[(long)(q0 + tx * 4 + i) * 128 + h * 32 + ty * 2 + 1], acc[i][1]);
    }
}

// ---------------------------------------------------------------------------
// Launch 5: attn_post — 256 blocks x 4 q-rows: attended = ctx@outw^T+outb,
// gs column sums, n1h = attended @ W1[:,128:]^T (f16).
// ---------------------------------------------------------------------------
__launch_bounds__(256)
__global__ void attn_post(const float* __restrict__ ctx, const float* __restrict__ outw,
                          const float* __restrict__ outb, const float* __restrict__ W1,
                          unsigned short* __restrict__ n1h, float* __restrict__ gs)
{
    __shared__ float ctxs[4][128];
    __shared__ float attr[4][128];
    const int t = threadIdx.x;
    const int q0 = blockIdx.x * 4;

    *(float2*)&ctxs[0][0] + 0;  // no-op
    {
        float2 v = *(const float2*)&ctx[(size_t)q0 * 128 + t * 2];
        ((float2*)&ctxs[0][0])[t] = v;
    }
    __syncthreads();

    // out-projection, row-local
    {
        const int j = t & 127, qp = t >> 7;
        float a0 = outb[j], a1 = a0;
        const float* wr = &outw[j * 128];
        for (int d = 0; d < 128; d += 4) {
            float4 w  = *(const float4*)&wr[d];
            float4 c0 = *(const float4*)&ctxs[qp * 2 + 0][d];
            float4 c1 = *(const float4*)&ctxs[qp * 2 + 1][d];
            a0 += w.x * c0.x + w.y * c0.y + w.z * c0.z + w.w * c0.w;
            a1 += w.x * c1.x + w.y * c1.y + w.z * c1.z + w.w * c1.w;
        }
        attr[qp * 2 + 0][j] = a0;
        attr[qp * 2 + 1][j] = a1;
    }
    __syncthreads();
    if (t < 128) atomicAdd(&gs[t], attr[0][t] + attr[1][t] + attr[2][t] + attr[3][t]);

    // n1h rows
    {
        const int c = t;
        const float* wr = &W1[c * 256 + 128];
        float n[4] = {};
        for (int d = 0; d < 128; d += 4) {
            float4 w = *(const float4*)&wr[d];
#pragma unroll
            for (int q = 0; q < 4; q++) {
                float4 a = *(const float4*)&attr[q][d];
                n[q] += w.x * a.x + w.y * a.y + w.z * a.z + w.w * a.w;
            }
        }
#pragma unroll
        for (int q = 0; q < 4; q++)
            n1h[(size_t)(q0 + q) * 256 + c] = __half_as_ushort(__float2half(n[q]));
    }
}

// ---------------------------------------------------------------------------
// Launch 6: matching scores (grid 16x33; y==32 hosts coord head).
// Best-known config: full-LDS W2, JIT global t-loads, swapped operands,
// zero-init acc, b2/W3 LDS tables in epilogue, no prefetch.
// ---------------------------------------------------------------------------
__launch_bounds__(256, 2)
__global__ void score_kernel(const unsigned short* __restrict__ t1h,
                             const unsigned short* __restrict__ n1h,
                             const unsigned short* __restrict__ w2f,
                             const float* __restrict__ b2, const float* __restrict__ W3,
                             const float* __restrict__ b3, float* __restrict__ out,
                             const float* __restrict__ gs,
                             const float* __restrict__ Wc1, const float* __restrict__ bc1,
                             const float* __restrict__ Wc2, const float* __restrict__ bc2,
                             float* __restrict__ outc)
{
    __shared__ unsigned short w2s[32768];   // 64 KB
    __shared__ float b2s[128], w3s[128];
    const int tid = threadIdx.x;

    if (blockIdx.y == 32) {
        if (blockIdx.x != 0) return;
        float* g  = (float*)w2s;
        float* hh = g + 128;
        if (tid < 128) g[tid] = gs[tid] * (1.0f / 1024.0f);
        __syncthreads();
        {
            float a = bc1[tid];
            const float* wr = &Wc1[tid * 128];
            for (int d = 0; d < 128; d += 4) {
                float4 w = *(const float4*)&wr[d];
                a += w.x * g[d] + w.y * g[d + 1] + w.z * g[d + 2] + w.w * g[d + 3];
            }
            hh[tid] = fmaxf(a, 0.f);
        }
        __syncthreads();
        if (tid < 32) {
            float a = bc2[tid];
            const float* wr = &Wc2[tid * 256];
            for (int c = 0; c < 256; c += 4) {
                float4 w = *(const float4*)&wr[c];
                a += w.x * hh[c] + w.y * hh[c + 1] + w.z * hh[c + 2] + w.w * hh[c + 3];
            }
            outc[tid] = a;
        }
        return;
    }

    const int lane = tid & 63;
    const int wv = tid >> 6;
    const int col = lane & 15;
    const int quad = lane >> 4;
    const int nb = blockIdx.x * 64 + wv * 16;
    const int tb = blockIdx.y * 32;

    // stage W2 fragments + tables -> LDS
    {
        const uint4* src = (const uint4*)w2f;
        uint4* dst = (uint4*)w2s;
#pragma unroll
        for (int i = 0; i < 16; i++) dst[tid + i * 256] = src[tid + i * 256];
        if (tid < 128) { b2s[tid] = b2[tid]; w3s[tid] = W3[tid]; }
    }

    // n1 slice for this lane (16 n-rows per wave), all K=256: 32 VGPRs
    const int myn = nb + col;
    uint4 n1p[8];
#pragma unroll
    for (int cc = 0; cc < 8; cc++)
        n1p[cc] = *(const uint4*)(n1h + (size_t)myn * 256 + cc * 32 + quad * 8);

    const float b3s = b3[0];
    __syncthreads();

    for (int tg = 0; tg < 8; tg++) {
        floatx4 acc[4][8] = {};   // zero init

#pragma unroll
        for (int cc = 0; cc < 8; cc++) {
            // just-in-time t-loads (L1-hot broadcast)
            uint4 tp[4];
#pragma unroll
            for (int tt = 0; tt < 4; tt++)
                tp[tt] = *(const uint4*)(t1h + (size_t)(tb + tg * 4 + tt) * 256 + cc * 32 + quad * 8);

            const unsigned* npu = (const unsigned*)&n1p[cc];
            union { unsigned u[4]; half8 h; } af[4];
#pragma unroll
            for (int tt = 0; tt < 4; tt++) {
                const unsigned* tpu = (const unsigned*)&tp[tt];
#pragma unroll
                for (int p = 0; p < 4; p++)
                    af[tt].u[p] = pkmax(pkadd(tpu[p], npu[p]), 0u);
            }
#pragma unroll
            for (int ot = 0; ot < 8; ot++) {
                union { uint4 u; half8 h; } bf;
                bf.u = *(const uint4*)&w2s[((cc * 8 + ot) * 64 + lane) * 8];
#pragma unroll
                for (int tt = 0; tt < 4; tt++)   // A = W2-frag, B = h1-frag
                    acc[tt][ot] = __builtin_amdgcn_mfma_f32_16x16x32_f16(bf.h, af[tt].h, acc[tt][ot], 0, 0, 0);
            }
        }

        // epilogue: b2 + relu + W3 from LDS tables, in-lane reduce + 2 shuffles
        float part[4] = {0.f, 0.f, 0.f, 0.f};
#pragma unroll
        for (int ot = 0; ot < 8; ot++) {
            float4 bq = *(const float4*)&b2s[ot * 16 + quad * 4];
            float4 wq = *(const float4*)&w3s[ot * 16 + quad * 4];
#pragma unroll
            for (int tt = 0; tt < 4; tt++) {
                floatx4 a = acc[tt][ot];
                part[tt] += fmaxf(a[0] + bq.x, 0.f) * wq.x + fmaxf(a[1] + bq.y, 0.f) * wq.y
                          + fmaxf(a[2] + bq.z, 0.f) * wq.z + fmaxf(a[3] + bq.w, 0.f) * wq.w;
            }
        }
        float outv = 0.f;
#pragma unroll
        for (int tt = 0; tt < 4; tt++) {
            float p = part[tt];
            p += __shfl_xor(p, 16);
            p += __shfl_xor(p, 32);
            if (quad == tt) outv = p;   // quad q keeps t = tg*4 + q
        }
        out[(size_t)(tb + tg * 4 + quad) * 1024 + nb + col] =
            1.0f / (1.0f + __expf(-(outv + b3s)));
    }
}

// ---------------------------------------------------------------------------
extern "C" void kernel_launch(void* const* d_in, const int* in_sizes, int n_in,
                              void* d_out, int out_size, void* d_ws, size_t ws_size,
                              hipStream_t stream)
{
    const float* node = (const float*)d_in[0];
    const float* task = (const float*)d_in[1];
    const float* ipw  = (const float*)d_in[2];
    const float* ipb  = (const float*)d_in[3];
    const float* outw = (const float*)d_in[4];
    const float* outb = (const float*)d_in[5];
    const float* W1   = (const float*)d_in[6];
    const float* b1   = (const float*)d_in[7];
    const float* W2   = (const float*)d_in[8];
    const float* b2   = (const float*)d_in[9];
    const float* W3   = (const float*)d_in[10];
    const float* b3   = (const float*)d_in[11];
    const float* Wc1  = (const float*)d_in[12];
    const float* bc1  = (const float*)d_in[13];
    const float* Wc2  = (const float*)d_in[14];
    const float* bc2  = (const float*)d_in[15];

    char* ws = (char*)d_ws;
    float* qkv = (float*)(ws + OFF_QKV);
    float* ctx = (float*)(ws + OFF_CTX);
    unsigned short* t1h = (unsigned short*)(ws + OFF_T1H);
    unsigned short* n1h = (unsigned short*)(ws + OFF_N1H);
    unsigned short* w2f = (unsigned short*)(ws + OFF_W2F);
    float* gs = (float*)(ws + OFF_GS);
    unsigned short* sc16 = (unsigned short*)(ws + OFF_SC);
    unsigned short* Pg   = (unsigned short*)(ws + OFF_PG);

    float* out_match = (float*)d_out;
    float* out_coord = out_match + 1048576;
    float* out_attn  = out_coord + 32;

    hipMemsetAsync(ctx, 0, 1024 * 128 * 4, stream);
    // 1. qkv + t1h + w2prep + gs zero
    proj_fused<<<dim3(177, 1, 1), 256, 0, stream>>>(
        node, ipw, ipb, task, W1, b1, W2, qkv, t1h, w2f, gs);
    // 2. raw scores (f16)
    scores_kernel<<<dim3(16, 16, 4), 256, 0, stream>>>(qkv, sc16);
    // 3. softmax stats + probs + attn_w
    attn_pre<<<dim3(1024, 1, 1), 256, 0, stream>>>(sc16, Pg, out_attn);
    // 4. ctx = P @ V (split-k)
    ctx_kernel<<<dim3(16, 8, 4), 256, 0, stream>>>(Pg, qkv, ctx);
    // 5. out-proj + gs + n1h
    attn_post<<<dim3(256, 1, 1), 256, 0, stream>>>(ctx, outw, outb, W1, n1h, gs);
    // 6. matching scores + coord head
    score_kernel<<<dim3(16, 33, 1), 256, 0, stream>>>(
        t1h, n1h, w2f, b2, W3, b3, out_match,
        gs, Wc1, bc1, Wc2, bc2, out_coord);
}